// Round 10
// baseline (1665.914 us; speedup 1.0000x reference)
//
#include <hip/hip_runtime.h>

#define NU 200000
#define NR 50000
#define DD 64
#define NE 2000000
#define NQ 500000
#define SCAN_ITEMS 1024

// -------------------- degree count (int) --------------------
__global__ void count_int_kernel(const int* __restrict__ dst, int* __restrict__ cnt, int n) {
    int i = blockIdx.x * blockDim.x + threadIdx.x;
    if (i < n) atomicAdd(&cnt[dst[i]], 1);
}

// -------------------- scan: per-block reduce --------------------
__global__ void scan_reduce_kernel(const int* __restrict__ cnt, int* __restrict__ bsum, int n) {
    __shared__ int s[256];
    int base = blockIdx.x * SCAN_ITEMS;
    int t = 0;
    for (int i = threadIdx.x; i < SCAN_ITEMS; i += 256) {
        int g = base + i;
        t += (g < n) ? cnt[g] : 0;
    }
    s[threadIdx.x] = t;
    __syncthreads();
    for (int off = 128; off > 0; off >>= 1) {
        if (threadIdx.x < off) s[threadIdx.x] += s[threadIdx.x + off];
        __syncthreads();
    }
    if (threadIdx.x == 0) bsum[blockIdx.x] = s[0];
}

// -------------------- scan: single-block exclusive scan of block sums ------
__global__ void scan_bsum_kernel(int* __restrict__ bsum, int nb) {
    __shared__ int a[256], b[256];
    int tid = threadIdx.x;
    a[tid] = (tid < nb) ? bsum[tid] : 0;
    __syncthreads();
    int* cur = a; int* alt = b;
    for (int off = 1; off < 256; off <<= 1) {
        int t = cur[tid];
        if (tid >= off) t += cur[tid - off];
        alt[tid] = t;
        __syncthreads();
        int* tmp = cur; cur = alt; alt = tmp;
    }
    int excl = (tid == 0) ? 0 : cur[tid - 1];
    if (tid < nb) bsum[tid] = excl;
}

// -------------------- scan: write exclusive row starts --------------------
__global__ void scan_write_kernel(const int* __restrict__ cnt, const int* __restrict__ bsum,
                                  int* __restrict__ rs, int n, int total) {
    __shared__ int sa[256], sb[256];
    int tid = threadIdx.x;
    int base = blockIdx.x * SCAN_ITEMS;
    int loc[4];
    int t = 0;
#pragma unroll
    for (int i = 0; i < 4; i++) {
        int g = base + tid * 4 + i;
        int v = (g < n) ? cnt[g] : 0;
        loc[i] = t;
        t += v;
    }
    sa[tid] = t;
    __syncthreads();
    int* cur = sa; int* alt = sb;
    for (int off = 1; off < 256; off <<= 1) {
        int x = cur[tid];
        if (tid >= off) x += cur[tid - off];
        alt[tid] = x;
        __syncthreads();
        int* tmp = cur; cur = alt; alt = tmp;
    }
    int texcl = cur[tid] - t;
    int off0 = bsum[blockIdx.x] + texcl;
#pragma unroll
    for (int i = 0; i < 4; i++) {
        int g = base + tid * 4 + i;
        if (g < n) rs[g] = off0 + loc[i];
    }
    if (blockIdx.x == 0 && tid == 0) rs[n] = total;
}

// -------------------- CSR fill --------------------
__global__ void fill_csr_kernel(const int* __restrict__ src, const int* __restrict__ dst,
                                const int* __restrict__ rs, int* __restrict__ cursor,
                                int* __restrict__ csr, int n) {
    int e = blockIdx.x * blockDim.x + threadIdx.x;
    if (e < n) {
        int d = dst[e];
        int pos = atomicAdd(&cursor[d], 1);
        csr[rs[d] + pos] = src[e];
    }
}

// -------------------- gather mean: wave per dst row --------------------
__global__ __launch_bounds__(256)
void gather_mean_kernel(const float* __restrict__ h, const int* __restrict__ csr,
                        const int* __restrict__ rs, float* __restrict__ mean, int nrows) {
    int lane = threadIdx.x & 63;
    int wave = blockIdx.x * 4 + (threadIdx.x >> 6);
    if (wave >= nrows) return;
    int r = wave;
    int s = rs[r], e = rs[r + 1];
    float a0 = 0.f, a1 = 0.f, a2 = 0.f, a3 = 0.f;
    for (int j = s; j < e; j += 64) {
        int rem = e - j;
        int nch = rem < 64 ? rem : 64;
        int li = lane < nch ? lane : nch - 1;
        int idx = csr[j + li];
        for (int kk = 0; kk < nch; kk += 4) {
            int i0 = __shfl(idx, kk);
            int i1 = __shfl(idx, kk + 1);
            int i2 = __shfl(idx, kk + 2);
            int i3 = __shfl(idx, kk + 3);
            float v0 = h[i0 * DD + lane];
            float v1 = h[i1 * DD + lane];
            float v2 = h[i2 * DD + lane];
            float v3 = h[i3 * DD + lane];
            a0 += v0;
            a1 += (kk + 1 < nch) ? v1 : 0.f;
            a2 += (kk + 2 < nch) ? v2 : 0.f;
            a3 += (kk + 3 < nch) ? v3 : 0.f;
        }
    }
    float acc = (a0 + a1) + (a2 + a3);
    float inv = 1.0f / fmaxf((float)(e - s), 1.0f);
    mean[r * DD + lane] = acc * inv;
}

// ==== macro toolkit ====
// 4 rows/queries per thread (A..D) x 16 cols per wave: each LDS weight
// broadcast read feeds 4x the FMAs -> DS pipe no longer binding.
// Accumulators are 64 NAMED scalars (arrays become scratch on this compiler).
#define DOT4(A, B) ((A).x*(B).x + (A).y*(B).y + (A).z*(B).z + (A).w*(B).w)

#define SDECL(j) float sA##j = bsh[cb + (j)], sB##j = sA##j, sC##j = sA##j, sD##j = sA##j;

#define SCOL(j) { \
    const float4* wlp_ = (const float4*)(Wls + ((cb + (j)) << 6) + kc); \
    const float4* wrp_ = (const float4*)(Wrs + ((cb + (j)) << 6) + kc); \
    float4 l0_ = wlp_[0], l1_ = wlp_[1], q0_ = wrp_[0], q1_ = wrp_[1]; \
    sA##j += DOT4(mA0,l0_)+DOT4(mA1,l1_)+DOT4(xA0,q0_)+DOT4(xA1,q1_); \
    sB##j += DOT4(mB0,l0_)+DOT4(mB1,l1_)+DOT4(xB0,q0_)+DOT4(xB1,q1_); \
    sC##j += DOT4(mC0,l0_)+DOT4(mC1,l1_)+DOT4(xC0,q0_)+DOT4(xC1,q1_); \
    sD##j += DOT4(mD0,l0_)+DOT4(mD1,l1_)+DOT4(xD0,q0_)+DOT4(xD1,q1_); }

#define SRELU(j) { sA##j = fmaxf(sA##j,0.f); sB##j = fmaxf(sB##j,0.f); \
                   sC##j = fmaxf(sC##j,0.f); sD##j = fmaxf(sD##j,0.f); }

#define STORE_ROW(SR, rr, dst_) if ((rr) < n) { \
    float* o_ = dst_ + (size_t)(rr) * DD + cb; \
    *(float4*)(o_)      = {SR##0,  SR##1,  SR##2,  SR##3}; \
    *(float4*)(o_ + 4)  = {SR##4,  SR##5,  SR##6,  SR##7}; \
    *(float4*)(o_ + 8)  = {SR##8,  SR##9,  SR##10, SR##11}; \
    *(float4*)(o_ + 12) = {SR##12, SR##13, SR##14, SR##15}; }

// -------------------- SAGE linear: 4 rows/thread, 16 cols/wave ------------
__global__ __launch_bounds__(256, 2)
void sage_linear_kernel(const float* __restrict__ mean, const float* __restrict__ h,
                        const float* __restrict__ Wl, const float* __restrict__ Wr,
                        const float* __restrict__ bias,
                        float* __restrict__ out, int n, int do_relu) {
    __shared__ float Wls[DD * DD];
    __shared__ float Wrs[DD * DD];
    __shared__ float bsh[DD];
    for (int i = threadIdx.x; i < DD * DD; i += 256) {
        Wls[i] = Wl[i];
        Wrs[i] = Wr[i];
    }
    if (threadIdx.x < DD) bsh[threadIdx.x] = bias[threadIdx.x];
    __syncthreads();
    int lane = threadIdx.x & 63;
    int cb = (threadIdx.x >> 6) * 16;              // col group of this wave
    int r0 = blockIdx.x * 256 + lane;              // rows r0, +64, +128, +192
    int rA = min(r0, n - 1), rB = min(r0 + 64, n - 1);
    int rC = min(r0 + 128, n - 1), rD = min(r0 + 192, n - 1);
    const float *mA = mean + (size_t)rA * DD, *xA = h + (size_t)rA * DD;
    const float *mB = mean + (size_t)rB * DD, *xB = h + (size_t)rB * DD;
    const float *mC = mean + (size_t)rC * DD, *xC = h + (size_t)rC * DD;
    const float *mD = mean + (size_t)rD * DD, *xD = h + (size_t)rD * DD;
    SDECL(0)  SDECL(1)  SDECL(2)  SDECL(3)  SDECL(4)  SDECL(5)  SDECL(6)  SDECL(7)
    SDECL(8)  SDECL(9)  SDECL(10) SDECL(11) SDECL(12) SDECL(13) SDECL(14) SDECL(15)
#pragma unroll 1
    for (int kc = 0; kc < DD; kc += 8) {
        float4 mA0 = *(const float4*)(mA + kc), mA1 = *(const float4*)(mA + kc + 4);
        float4 xA0 = *(const float4*)(xA + kc), xA1 = *(const float4*)(xA + kc + 4);
        float4 mB0 = *(const float4*)(mB + kc), mB1 = *(const float4*)(mB + kc + 4);
        float4 xB0 = *(const float4*)(xB + kc), xB1 = *(const float4*)(xB + kc + 4);
        float4 mC0 = *(const float4*)(mC + kc), mC1 = *(const float4*)(mC + kc + 4);
        float4 xC0 = *(const float4*)(xC + kc), xC1 = *(const float4*)(xC + kc + 4);
        float4 mD0 = *(const float4*)(mD + kc), mD1 = *(const float4*)(mD + kc + 4);
        float4 xD0 = *(const float4*)(xD + kc), xD1 = *(const float4*)(xD + kc + 4);
        SCOL(0)  SCOL(1)  SCOL(2)  SCOL(3)  SCOL(4)  SCOL(5)  SCOL(6)  SCOL(7)
        SCOL(8)  SCOL(9)  SCOL(10) SCOL(11) SCOL(12) SCOL(13) SCOL(14) SCOL(15)
    }
    if (do_relu) {
        SRELU(0)  SRELU(1)  SRELU(2)  SRELU(3)  SRELU(4)  SRELU(5)  SRELU(6)  SRELU(7)
        SRELU(8)  SRELU(9)  SRELU(10) SRELU(11) SRELU(12) SRELU(13) SRELU(14) SRELU(15)
    }
    STORE_ROW(sA, r0, out)
    STORE_ROW(sB, r0 + 64, out)
    STORE_ROW(sC, r0 + 128, out)
    STORE_ROW(sD, r0 + 192, out)
}

// -------------------- decoder layer-1 precompute: same tiling --------------
#define PCOL(j) { \
    const float4* wp_ = (const float4*)(Ws + ((cb + (j)) << 6) + kc); \
    float4 w0_ = wp_[0], w1_ = wp_[1]; \
    sA##j += DOT4(xA0,w0_)+DOT4(xA1,w1_); \
    sB##j += DOT4(xB0,w0_)+DOT4(xB1,w1_); \
    sC##j += DOT4(xC0,w0_)+DOT4(xC1,w1_); \
    sD##j += DOT4(xD0,w0_)+DOT4(xD1,w1_); }

__global__ __launch_bounds__(256, 2)
void precompute_kernel(const float* __restrict__ h, const float* __restrict__ dW1,
                       const float* __restrict__ db1, float* __restrict__ P,
                       int n, int koff, int add_bias) {
    __shared__ float Ws[DD * DD];
    __shared__ float bsh[DD];
    for (int i = threadIdx.x; i < DD * DD; i += 256) {
        int c = i >> 6, k = i & 63;
        Ws[c * DD + k] = dW1[c * 2 * DD + koff + k];
    }
    if (threadIdx.x < DD) bsh[threadIdx.x] = add_bias ? db1[threadIdx.x] : 0.f;
    __syncthreads();
    int lane = threadIdx.x & 63;
    int cb = (threadIdx.x >> 6) * 16;
    int r0 = blockIdx.x * 256 + lane;
    int rA = min(r0, n - 1), rB = min(r0 + 64, n - 1);
    int rC = min(r0 + 128, n - 1), rD = min(r0 + 192, n - 1);
    const float *xA = h + (size_t)rA * DD, *xB = h + (size_t)rB * DD;
    const float *xC = h + (size_t)rC * DD, *xD = h + (size_t)rD * DD;
    SDECL(0)  SDECL(1)  SDECL(2)  SDECL(3)  SDECL(4)  SDECL(5)  SDECL(6)  SDECL(7)
    SDECL(8)  SDECL(9)  SDECL(10) SDECL(11) SDECL(12) SDECL(13) SDECL(14) SDECL(15)
#pragma unroll 1
    for (int kc = 0; kc < DD; kc += 8) {
        float4 xA0 = *(const float4*)(xA + kc), xA1 = *(const float4*)(xA + kc + 4);
        float4 xB0 = *(const float4*)(xB + kc), xB1 = *(const float4*)(xB + kc + 4);
        float4 xC0 = *(const float4*)(xC + kc), xC1 = *(const float4*)(xC + kc + 4);
        float4 xD0 = *(const float4*)(xD + kc), xD1 = *(const float4*)(xD + kc + 4);
        PCOL(0)  PCOL(1)  PCOL(2)  PCOL(3)  PCOL(4)  PCOL(5)  PCOL(6)  PCOL(7)
        PCOL(8)  PCOL(9)  PCOL(10) PCOL(11) PCOL(12) PCOL(13) PCOL(14) PCOL(15)
    }
    STORE_ROW(sA, r0, P)
    STORE_ROW(sB, r0 + 64, P)
    STORE_ROW(sC, r0 + 128, P)
    STORE_ROW(sD, r0 + 192, P)
}

// -------------------- fused decoder: 4 queries/thread, 16 cols/wave --------
// NOTE: z var names passed explicitly (token-pasting z##R##0.x is invalid:
// "0.x" is a single pp-number token).
#define ZMAKE(PUP, PRP, Z0, Z1) \
    { float4 u_ = *(const float4*)(PUP + kc);     float4 v_ = *(const float4*)(PRP + kc); \
      Z0.x = fmaxf(u_.x+v_.x,0.f); Z0.y = fmaxf(u_.y+v_.y,0.f); \
      Z0.z = fmaxf(u_.z+v_.z,0.f); Z0.w = fmaxf(u_.w+v_.w,0.f); } \
    { float4 u_ = *(const float4*)(PUP + kc + 4); float4 v_ = *(const float4*)(PRP + kc + 4); \
      Z1.x = fmaxf(u_.x+v_.x,0.f); Z1.y = fmaxf(u_.y+v_.y,0.f); \
      Z1.z = fmaxf(u_.z+v_.z,0.f); Z1.w = fmaxf(u_.w+v_.w,0.f); }

#define DCOL(j) { \
    const float4* wp_ = (const float4*)(W2s + ((cb + (j)) << 6) + kc); \
    float4 w0_ = wp_[0], w1_ = wp_[1]; \
    sA##j += DOT4(zA0,w0_)+DOT4(zA1,w1_); \
    sB##j += DOT4(zB0,w0_)+DOT4(zB1,w1_); \
    sC##j += DOT4(zC0,w0_)+DOT4(zC1,w1_); \
    sD##j += DOT4(zD0,w0_)+DOT4(zD1,w1_); }

#define DFIN(j) { float w3_ = w3s[cb + (j)]; \
    oA += fmaxf(sA##j, 0.f) * w3_; oB += fmaxf(sB##j, 0.f) * w3_; \
    oC += fmaxf(sC##j, 0.f) * w3_; oD += fmaxf(sD##j, 0.f) * w3_; }

__global__ __launch_bounds__(256, 2)
void decoder_kernel(const float* __restrict__ Pu, const float* __restrict__ Pr,
                    const int* __restrict__ el_row, const int* __restrict__ el_col,
                    const float* __restrict__ dW2, const float* __restrict__ db2,
                    const float* __restrict__ dW3, const float* __restrict__ db3,
                    float* __restrict__ out) {
    __shared__ float W2s[DD * DD];
    __shared__ float red[4 * 256];
    __shared__ float bsh[DD], w3s[DD];
    for (int i = threadIdx.x; i < DD * DD; i += 256) W2s[i] = dW2[i];
    if (threadIdx.x < DD) {
        bsh[threadIdx.x] = db2[threadIdx.x];
        w3s[threadIdx.x] = dW3[threadIdx.x];
    }
    __syncthreads();
    int lane = threadIdx.x & 63;
    int wv = threadIdx.x >> 6;
    int cb = wv * 16;
    int q0 = blockIdx.x * 256 + lane;
    int qA = min(q0, NQ - 1), qB = min(q0 + 64, NQ - 1);
    int qC = min(q0 + 128, NQ - 1), qD = min(q0 + 192, NQ - 1);
    const float* puA = Pu + (size_t)el_row[qA] * DD;
    const float* prA = Pr + (size_t)el_col[qA] * DD;
    const float* puB = Pu + (size_t)el_row[qB] * DD;
    const float* prB = Pr + (size_t)el_col[qB] * DD;
    const float* puC = Pu + (size_t)el_row[qC] * DD;
    const float* prC = Pr + (size_t)el_col[qC] * DD;
    const float* puD = Pu + (size_t)el_row[qD] * DD;
    const float* prD = Pr + (size_t)el_col[qD] * DD;
    SDECL(0)  SDECL(1)  SDECL(2)  SDECL(3)  SDECL(4)  SDECL(5)  SDECL(6)  SDECL(7)
    SDECL(8)  SDECL(9)  SDECL(10) SDECL(11) SDECL(12) SDECL(13) SDECL(14) SDECL(15)
#pragma unroll 1
    for (int kc = 0; kc < DD; kc += 8) {
        float4 zA0, zA1, zB0, zB1, zC0, zC1, zD0, zD1;
        ZMAKE(puA, prA, zA0, zA1)
        ZMAKE(puB, prB, zB0, zB1)
        ZMAKE(puC, prC, zC0, zC1)
        ZMAKE(puD, prD, zD0, zD1)
        DCOL(0)  DCOL(1)  DCOL(2)  DCOL(3)  DCOL(4)  DCOL(5)  DCOL(6)  DCOL(7)
        DCOL(8)  DCOL(9)  DCOL(10) DCOL(11) DCOL(12) DCOL(13) DCOL(14) DCOL(15)
    }
    float oA = 0.f, oB = 0.f, oC = 0.f, oD = 0.f;
    DFIN(0)  DFIN(1)  DFIN(2)  DFIN(3)  DFIN(4)  DFIN(5)  DFIN(6)  DFIN(7)
    DFIN(8)  DFIN(9)  DFIN(10) DFIN(11) DFIN(12) DFIN(13) DFIN(14) DFIN(15)
    red[wv * 256 + lane]       = oA;
    red[wv * 256 + lane + 64]  = oB;
    red[wv * 256 + lane + 128] = oC;
    red[wv * 256 + lane + 192] = oD;
    __syncthreads();
    int t = threadIdx.x;
    int q = blockIdx.x * 256 + t;
    if (q < NQ) {
        out[q] = red[t] + red[256 + t] + red[512 + t] + red[768 + t] + db3[0];
    }
}

extern "C" void kernel_launch(void* const* d_in, const int* in_sizes, int n_in,
                              void* d_out, int out_size, void* d_ws, size_t ws_size,
                              hipStream_t stream) {
    const float* x_user = (const float*)d_in[0];
    const float* x_rest = (const float*)d_in[1];
    const float* Wl     = (const float*)d_in[2];
    const float* Wr     = (const float*)d_in[3];
    const float* bl     = (const float*)d_in[4];
    const float* dW1    = (const float*)d_in[5];
    const float* db1    = (const float*)d_in[6];
    const float* dW2    = (const float*)d_in[7];
    const float* db2    = (const float*)d_in[8];
    const float* dW3    = (const float*)d_in[9];
    const float* db3    = (const float*)d_in[10];
    const int* ur_src   = (const int*)d_in[11];
    const int* ur_dst   = (const int*)d_in[12];
    const int* ru_src   = (const int*)d_in[13];
    const int* ru_dst   = (const int*)d_in[14];
    const int* el_row   = (const int*)d_in[15];
    const int* el_col   = (const int*)d_in[16];
    float* out = (float*)d_out;

    char* w = (char*)d_ws;
    size_t off = 0;
    auto alloc = [&](size_t bytes) -> void* {
        void* p = (void*)(w + off);
        off += (bytes + 255) & ~(size_t)255;
        return p;
    };
    float* hu0  = (float*)alloc((size_t)NU * DD * 4);
    float* hu1  = (float*)alloc((size_t)NU * DD * 4);
    float* hr0  = (float*)alloc((size_t)NR * DD * 4);
    float* hr1  = (float*)alloc((size_t)NR * DD * 4);
    float* mean = (float*)alloc((size_t)NU * DD * 4);
    int* csr_u  = (int*)alloc((size_t)NE * 4);
    int* csr_r  = (int*)alloc((size_t)NE * 4);
    int* rs_u   = (int*)alloc((size_t)(NU + 1) * 4);
    int* rs_r   = (int*)alloc((size_t)(NR + 1) * 4);
    int* cnt_u  = (int*)alloc((size_t)NU * 4);
    int* cnt_r  = (int*)alloc((size_t)NR * 4);
    int* bsum_u = (int*)alloc(256 * 4);
    int* bsum_r = (int*)alloc(256 * 4);

    const int nb_u = (NU + SCAN_ITEMS - 1) / SCAN_ITEMS;
    const int nb_r = (NR + SCAN_ITEMS - 1) / SCAN_ITEMS;
    const int egrid = (NE + 255) / 256;

    hipMemsetAsync(cnt_u, 0, (size_t)NU * 4, stream);
    hipMemsetAsync(cnt_r, 0, (size_t)NR * 4, stream);
    count_int_kernel<<<egrid, 256, 0, stream>>>(ru_dst, cnt_u, NE);
    count_int_kernel<<<egrid, 256, 0, stream>>>(ur_dst, cnt_r, NE);
    scan_reduce_kernel<<<nb_u, 256, 0, stream>>>(cnt_u, bsum_u, NU);
    scan_bsum_kernel<<<1, 256, 0, stream>>>(bsum_u, nb_u);
    scan_write_kernel<<<nb_u, 256, 0, stream>>>(cnt_u, bsum_u, rs_u, NU, NE);
    scan_reduce_kernel<<<nb_r, 256, 0, stream>>>(cnt_r, bsum_r, NR);
    scan_bsum_kernel<<<1, 256, 0, stream>>>(bsum_r, nb_r);
    scan_write_kernel<<<nb_r, 256, 0, stream>>>(cnt_r, bsum_r, rs_r, NR, NE);
    hipMemsetAsync(cnt_u, 0, (size_t)NU * 4, stream);
    hipMemsetAsync(cnt_r, 0, (size_t)NR * 4, stream);
    fill_csr_kernel<<<egrid, 256, 0, stream>>>(ru_src, ru_dst, rs_u, cnt_u, csr_u, NE);
    fill_csr_kernel<<<egrid, 256, 0, stream>>>(ur_src, ur_dst, rs_r, cnt_r, csr_r, NE);

    const float* cu = x_user;
    const float* cr = x_rest;
    float* nu_[3] = {hu0, hu1, hu0};
    float* nr_[3] = {hr0, hr1, hr0};

    for (int l = 0; l < 3; l++) {
        const float* Wl_r = Wl + (size_t)(l * 2 + 0) * DD * DD;
        const float* Wr_r = Wr + (size_t)(l * 2 + 0) * DD * DD;
        const float* bl_r = bl + (size_t)(l * 2 + 0) * DD;
        const float* Wl_u = Wl + (size_t)(l * 2 + 1) * DD * DD;
        const float* Wr_u = Wr + (size_t)(l * 2 + 1) * DD * DD;
        const float* bl_u = bl + (size_t)(l * 2 + 1) * DD;
        int relu = (l < 2) ? 1 : 0;

        gather_mean_kernel<<<(NR + 3) / 4, 256, 0, stream>>>(cu, csr_r, rs_r, mean, NR);
        sage_linear_kernel<<<(NR + 255) / 256, 256, 0, stream>>>(mean, cr, Wl_r, Wr_r, bl_r, nr_[l], NR, relu);
        gather_mean_kernel<<<(NU + 3) / 4, 256, 0, stream>>>(cr, csr_u, rs_u, mean, NU);
        sage_linear_kernel<<<(NU + 255) / 256, 256, 0, stream>>>(mean, cu, Wl_u, Wr_u, bl_u, nu_[l], NU, relu);

        cu = nu_[l];
        cr = nr_[l];
    }
    float* P_u = hu1;
    float* P_r = hr1;
    precompute_kernel<<<(NU + 255) / 256, 256, 0, stream>>>(cu, dW1, db1, P_u, NU, 0, 1);
    precompute_kernel<<<(NR + 255) / 256, 256, 0, stream>>>(cr, dW1, db1, P_r, NR, DD, 0);

    decoder_kernel<<<(NQ + 255) / 256, 256, 0, stream>>>(P_u, P_r, el_row, el_col,
                                                         dW2, db2, dW3, db3, out);
}

// Round 11
// 1624.666 us; speedup vs baseline: 1.0254x; 1.0254x over previous
//
#include <hip/hip_runtime.h>

#define NU 200000
#define NR 50000
#define DD 64
#define NE 2000000
#define NQ 500000
#define SCAN_ITEMS 1024

// -------------------- degree count (int) --------------------
__global__ void count_int_kernel(const int* __restrict__ dst, int* __restrict__ cnt, int n) {
    int i = blockIdx.x * blockDim.x + threadIdx.x;
    if (i < n) atomicAdd(&cnt[dst[i]], 1);
}

// -------------------- scan: per-block reduce --------------------
__global__ void scan_reduce_kernel(const int* __restrict__ cnt, int* __restrict__ bsum, int n) {
    __shared__ int s[256];
    int base = blockIdx.x * SCAN_ITEMS;
    int t = 0;
    for (int i = threadIdx.x; i < SCAN_ITEMS; i += 256) {
        int g = base + i;
        t += (g < n) ? cnt[g] : 0;
    }
    s[threadIdx.x] = t;
    __syncthreads();
    for (int off = 128; off > 0; off >>= 1) {
        if (threadIdx.x < off) s[threadIdx.x] += s[threadIdx.x + off];
        __syncthreads();
    }
    if (threadIdx.x == 0) bsum[blockIdx.x] = s[0];
}

// -------------------- scan: single-block exclusive scan of block sums ------
__global__ void scan_bsum_kernel(int* __restrict__ bsum, int nb) {
    __shared__ int a[256], b[256];
    int tid = threadIdx.x;
    a[tid] = (tid < nb) ? bsum[tid] : 0;
    __syncthreads();
    int* cur = a; int* alt = b;
    for (int off = 1; off < 256; off <<= 1) {
        int t = cur[tid];
        if (tid >= off) t += cur[tid - off];
        alt[tid] = t;
        __syncthreads();
        int* tmp = cur; cur = alt; alt = tmp;
    }
    int excl = (tid == 0) ? 0 : cur[tid - 1];
    if (tid < nb) bsum[tid] = excl;
}

// -------------------- scan: write exclusive row starts --------------------
__global__ void scan_write_kernel(const int* __restrict__ cnt, const int* __restrict__ bsum,
                                  int* __restrict__ rs, int n, int total) {
    __shared__ int sa[256], sb[256];
    int tid = threadIdx.x;
    int base = blockIdx.x * SCAN_ITEMS;
    int loc[4];
    int t = 0;
#pragma unroll
    for (int i = 0; i < 4; i++) {
        int g = base + tid * 4 + i;
        int v = (g < n) ? cnt[g] : 0;
        loc[i] = t;
        t += v;
    }
    sa[tid] = t;
    __syncthreads();
    int* cur = sa; int* alt = sb;
    for (int off = 1; off < 256; off <<= 1) {
        int x = cur[tid];
        if (tid >= off) x += cur[tid - off];
        alt[tid] = x;
        __syncthreads();
        int* tmp = cur; cur = alt; alt = tmp;
    }
    int texcl = cur[tid] - t;
    int off0 = bsum[blockIdx.x] + texcl;
#pragma unroll
    for (int i = 0; i < 4; i++) {
        int g = base + tid * 4 + i;
        if (g < n) rs[g] = off0 + loc[i];
    }
    if (blockIdx.x == 0 && tid == 0) rs[n] = total;
}

// -------------------- CSR fill --------------------
__global__ void fill_csr_kernel(const int* __restrict__ src, const int* __restrict__ dst,
                                const int* __restrict__ rs, int* __restrict__ cursor,
                                int* __restrict__ csr, int n) {
    int e = blockIdx.x * blockDim.x + threadIdx.x;
    if (e < n) {
        int d = dst[e];
        int pos = atomicAdd(&cursor[d], 1);
        csr[rs[d] + pos] = src[e];
    }
}

// -------------------- gather mean: wave per dst row --------------------
__global__ __launch_bounds__(256)
void gather_mean_kernel(const float* __restrict__ h, const int* __restrict__ csr,
                        const int* __restrict__ rs, float* __restrict__ mean, int nrows) {
    int lane = threadIdx.x & 63;
    int wave = blockIdx.x * 4 + (threadIdx.x >> 6);
    if (wave >= nrows) return;
    int r = wave;
    int s = rs[r], e = rs[r + 1];
    float a0 = 0.f, a1 = 0.f, a2 = 0.f, a3 = 0.f;
    for (int j = s; j < e; j += 64) {
        int rem = e - j;
        int nch = rem < 64 ? rem : 64;
        int li = lane < nch ? lane : nch - 1;
        int idx = csr[j + li];
        for (int kk = 0; kk < nch; kk += 4) {
            int i0 = __shfl(idx, kk);
            int i1 = __shfl(idx, kk + 1);
            int i2 = __shfl(idx, kk + 2);
            int i3 = __shfl(idx, kk + 3);
            float v0 = h[i0 * DD + lane];
            float v1 = h[i1 * DD + lane];
            float v2 = h[i2 * DD + lane];
            float v3 = h[i3 * DD + lane];
            a0 += v0;
            a1 += (kk + 1 < nch) ? v1 : 0.f;
            a2 += (kk + 2 < nch) ? v2 : 0.f;
            a3 += (kk + 3 < nch) ? v3 : 0.f;
        }
    }
    float acc = (a0 + a1) + (a2 + a3);
    float inv = 1.0f / fmaxf((float)(e - s), 1.0f);
    mean[r * DD + lane] = acc * inv;
}

// ==== macro toolkit (sage/precompute: 4 rows/thread x 16 cols/wave) ====
#define DOT4(A, B) ((A).x*(B).x + (A).y*(B).y + (A).z*(B).z + (A).w*(B).w)

#define SDECL(j) float sA##j = bsh[cb + (j)], sB##j = sA##j, sC##j = sA##j, sD##j = sA##j;

#define SCOL(j) { \
    const float4* wlp_ = (const float4*)(Wls + ((cb + (j)) << 6) + kc); \
    const float4* wrp_ = (const float4*)(Wrs + ((cb + (j)) << 6) + kc); \
    float4 l0_ = wlp_[0], l1_ = wlp_[1], q0_ = wrp_[0], q1_ = wrp_[1]; \
    sA##j += DOT4(mA0,l0_)+DOT4(mA1,l1_)+DOT4(xA0,q0_)+DOT4(xA1,q1_); \
    sB##j += DOT4(mB0,l0_)+DOT4(mB1,l1_)+DOT4(xB0,q0_)+DOT4(xB1,q1_); \
    sC##j += DOT4(mC0,l0_)+DOT4(mC1,l1_)+DOT4(xC0,q0_)+DOT4(xC1,q1_); \
    sD##j += DOT4(mD0,l0_)+DOT4(mD1,l1_)+DOT4(xD0,q0_)+DOT4(xD1,q1_); }

#define SRELU(j) { sA##j = fmaxf(sA##j,0.f); sB##j = fmaxf(sB##j,0.f); \
                   sC##j = fmaxf(sC##j,0.f); sD##j = fmaxf(sD##j,0.f); }

#define STORE_ROW(SR, rr, dst_) if ((rr) < n) { \
    float* o_ = dst_ + (size_t)(rr) * DD + cb; \
    *(float4*)(o_)      = {SR##0,  SR##1,  SR##2,  SR##3}; \
    *(float4*)(o_ + 4)  = {SR##4,  SR##5,  SR##6,  SR##7}; \
    *(float4*)(o_ + 8)  = {SR##8,  SR##9,  SR##10, SR##11}; \
    *(float4*)(o_ + 12) = {SR##12, SR##13, SR##14, SR##15}; }

// -------------------- SAGE linear: 4 rows/thread, 16 cols/wave ------------
__global__ __launch_bounds__(256, 2)
void sage_linear_kernel(const float* __restrict__ mean, const float* __restrict__ h,
                        const float* __restrict__ Wl, const float* __restrict__ Wr,
                        const float* __restrict__ bias,
                        float* __restrict__ out, int n, int do_relu) {
    __shared__ float Wls[DD * DD];
    __shared__ float Wrs[DD * DD];
    __shared__ float bsh[DD];
    for (int i = threadIdx.x; i < DD * DD; i += 256) {
        Wls[i] = Wl[i];
        Wrs[i] = Wr[i];
    }
    if (threadIdx.x < DD) bsh[threadIdx.x] = bias[threadIdx.x];
    __syncthreads();
    int lane = threadIdx.x & 63;
    int cb = (threadIdx.x >> 6) * 16;
    int r0 = blockIdx.x * 256 + lane;
    int rA = min(r0, n - 1), rB = min(r0 + 64, n - 1);
    int rC = min(r0 + 128, n - 1), rD = min(r0 + 192, n - 1);
    const float *mA = mean + (size_t)rA * DD, *xA = h + (size_t)rA * DD;
    const float *mB = mean + (size_t)rB * DD, *xB = h + (size_t)rB * DD;
    const float *mC = mean + (size_t)rC * DD, *xC = h + (size_t)rC * DD;
    const float *mD = mean + (size_t)rD * DD, *xD = h + (size_t)rD * DD;
    SDECL(0)  SDECL(1)  SDECL(2)  SDECL(3)  SDECL(4)  SDECL(5)  SDECL(6)  SDECL(7)
    SDECL(8)  SDECL(9)  SDECL(10) SDECL(11) SDECL(12) SDECL(13) SDECL(14) SDECL(15)
#pragma unroll 1
    for (int kc = 0; kc < DD; kc += 8) {
        float4 mA0 = *(const float4*)(mA + kc), mA1 = *(const float4*)(mA + kc + 4);
        float4 xA0 = *(const float4*)(xA + kc), xA1 = *(const float4*)(xA + kc + 4);
        float4 mB0 = *(const float4*)(mB + kc), mB1 = *(const float4*)(mB + kc + 4);
        float4 xB0 = *(const float4*)(xB + kc), xB1 = *(const float4*)(xB + kc + 4);
        float4 mC0 = *(const float4*)(mC + kc), mC1 = *(const float4*)(mC + kc + 4);
        float4 xC0 = *(const float4*)(xC + kc), xC1 = *(const float4*)(xC + kc + 4);
        float4 mD0 = *(const float4*)(mD + kc), mD1 = *(const float4*)(mD + kc + 4);
        float4 xD0 = *(const float4*)(xD + kc), xD1 = *(const float4*)(xD + kc + 4);
        SCOL(0)  SCOL(1)  SCOL(2)  SCOL(3)  SCOL(4)  SCOL(5)  SCOL(6)  SCOL(7)
        SCOL(8)  SCOL(9)  SCOL(10) SCOL(11) SCOL(12) SCOL(13) SCOL(14) SCOL(15)
    }
    if (do_relu) {
        SRELU(0)  SRELU(1)  SRELU(2)  SRELU(3)  SRELU(4)  SRELU(5)  SRELU(6)  SRELU(7)
        SRELU(8)  SRELU(9)  SRELU(10) SRELU(11) SRELU(12) SRELU(13) SRELU(14) SRELU(15)
    }
    STORE_ROW(sA, r0, out)
    STORE_ROW(sB, r0 + 64, out)
    STORE_ROW(sC, r0 + 128, out)
    STORE_ROW(sD, r0 + 192, out)
}

// -------------------- decoder layer-1 precompute: same tiling --------------
#define PCOL(j) { \
    const float4* wp_ = (const float4*)(Ws + ((cb + (j)) << 6) + kc); \
    float4 w0_ = wp_[0], w1_ = wp_[1]; \
    sA##j += DOT4(xA0,w0_)+DOT4(xA1,w1_); \
    sB##j += DOT4(xB0,w0_)+DOT4(xB1,w1_); \
    sC##j += DOT4(xC0,w0_)+DOT4(xC1,w1_); \
    sD##j += DOT4(xD0,w0_)+DOT4(xD1,w1_); }

__global__ __launch_bounds__(256, 2)
void precompute_kernel(const float* __restrict__ h, const float* __restrict__ dW1,
                       const float* __restrict__ db1, float* __restrict__ P,
                       int n, int koff, int add_bias) {
    __shared__ float Ws[DD * DD];
    __shared__ float bsh[DD];
    for (int i = threadIdx.x; i < DD * DD; i += 256) {
        int c = i >> 6, k = i & 63;
        Ws[c * DD + k] = dW1[c * 2 * DD + koff + k];
    }
    if (threadIdx.x < DD) bsh[threadIdx.x] = add_bias ? db1[threadIdx.x] : 0.f;
    __syncthreads();
    int lane = threadIdx.x & 63;
    int cb = (threadIdx.x >> 6) * 16;
    int r0 = blockIdx.x * 256 + lane;
    int rA = min(r0, n - 1), rB = min(r0 + 64, n - 1);
    int rC = min(r0 + 128, n - 1), rD = min(r0 + 192, n - 1);
    const float *xA = h + (size_t)rA * DD, *xB = h + (size_t)rB * DD;
    const float *xC = h + (size_t)rC * DD, *xD = h + (size_t)rD * DD;
    SDECL(0)  SDECL(1)  SDECL(2)  SDECL(3)  SDECL(4)  SDECL(5)  SDECL(6)  SDECL(7)
    SDECL(8)  SDECL(9)  SDECL(10) SDECL(11) SDECL(12) SDECL(13) SDECL(14) SDECL(15)
#pragma unroll 1
    for (int kc = 0; kc < DD; kc += 8) {
        float4 xA0 = *(const float4*)(xA + kc), xA1 = *(const float4*)(xA + kc + 4);
        float4 xB0 = *(const float4*)(xB + kc), xB1 = *(const float4*)(xB + kc + 4);
        float4 xC0 = *(const float4*)(xC + kc), xC1 = *(const float4*)(xC + kc + 4);
        float4 xD0 = *(const float4*)(xD + kc), xD1 = *(const float4*)(xD + kc + 4);
        PCOL(0)  PCOL(1)  PCOL(2)  PCOL(3)  PCOL(4)  PCOL(5)  PCOL(6)  PCOL(7)
        PCOL(8)  PCOL(9)  PCOL(10) PCOL(11) PCOL(12) PCOL(13) PCOL(14) PCOL(15)
    }
    STORE_ROW(sA, r0, P)
    STORE_ROW(sB, r0 + 64, P)
    STORE_ROW(sC, r0 + 128, P)
    STORE_ROW(sD, r0 + 192, P)
}

// -------------------- fused decoder: 2 queries/thread, all 64 cols ---------
// Gather 1x per query (z resident in 32 named float4); each ds_read_b128 of
// the weight row feeds BOTH queries -> 8 DS/query (R8 was 16, R10 was 4 but
// with 4x gather re-reads).
#define ZD(Z, PUP, PRP, i) float4 Z; { \
    float4 u_ = (PUP)[i]; float4 v_ = (PRP)[i]; \
    Z.x = fmaxf(u_.x+v_.x,0.f); Z.y = fmaxf(u_.y+v_.y,0.f); \
    Z.z = fmaxf(u_.z+v_.z,0.f); Z.w = fmaxf(u_.w+v_.w,0.f); }

__global__ __launch_bounds__(256, 2)
void decoder_kernel(const float* __restrict__ Pu, const float* __restrict__ Pr,
                    const int* __restrict__ el_row, const int* __restrict__ el_col,
                    const float* __restrict__ dW2, const float* __restrict__ db2,
                    const float* __restrict__ dW3, const float* __restrict__ db3,
                    float* __restrict__ out) {
    __shared__ float W2s[DD * DD];
    __shared__ float b2s[DD], w3s[DD];
    for (int i = threadIdx.x; i < DD * DD; i += 256) W2s[i] = dW2[i];
    if (threadIdx.x < DD) {
        b2s[threadIdx.x] = db2[threadIdx.x];
        w3s[threadIdx.x] = dW3[threadIdx.x];
    }
    __syncthreads();
    int q = blockIdx.x * 512 + threadIdx.x;        // qA = q, qB = q + 256
    int qA = min(q, NQ - 1);
    int qB = min(q + 256, NQ - 1);
    const float4* puA = (const float4*)(Pu + (size_t)el_row[qA] * DD);
    const float4* prA = (const float4*)(Pr + (size_t)el_col[qA] * DD);
    const float4* puB = (const float4*)(Pu + (size_t)el_row[qB] * DD);
    const float4* prB = (const float4*)(Pr + (size_t)el_col[qB] * DD);
    ZD(zA0, puA, prA, 0)   ZD(zA1, puA, prA, 1)   ZD(zA2, puA, prA, 2)   ZD(zA3, puA, prA, 3)
    ZD(zA4, puA, prA, 4)   ZD(zA5, puA, prA, 5)   ZD(zA6, puA, prA, 6)   ZD(zA7, puA, prA, 7)
    ZD(zA8, puA, prA, 8)   ZD(zA9, puA, prA, 9)   ZD(zA10, puA, prA, 10) ZD(zA11, puA, prA, 11)
    ZD(zA12, puA, prA, 12) ZD(zA13, puA, prA, 13) ZD(zA14, puA, prA, 14) ZD(zA15, puA, prA, 15)
    ZD(zB0, puB, prB, 0)   ZD(zB1, puB, prB, 1)   ZD(zB2, puB, prB, 2)   ZD(zB3, puB, prB, 3)
    ZD(zB4, puB, prB, 4)   ZD(zB5, puB, prB, 5)   ZD(zB6, puB, prB, 6)   ZD(zB7, puB, prB, 7)
    ZD(zB8, puB, prB, 8)   ZD(zB9, puB, prB, 9)   ZD(zB10, puB, prB, 10) ZD(zB11, puB, prB, 11)
    ZD(zB12, puB, prB, 12) ZD(zB13, puB, prB, 13) ZD(zB14, puB, prB, 14) ZD(zB15, puB, prB, 15)
    float oA = 0.f, oB = 0.f;
#pragma unroll 2
    for (int c = 0; c < DD; c++) {
        const float4* wp = (const float4*)(W2s + (c << 6));
        float4 w0 = wp[0], w1 = wp[1], w2 = wp[2], w3 = wp[3];
        float sA = b2s[c]
            + DOT4(zA0, w0) + DOT4(zA1, w1) + DOT4(zA2, w2) + DOT4(zA3, w3);
        float sB = b2s[c]
            + DOT4(zB0, w0) + DOT4(zB1, w1) + DOT4(zB2, w2) + DOT4(zB3, w3);
        float4 w4 = wp[4], w5 = wp[5], w6 = wp[6], w7 = wp[7];
        sA += DOT4(zA4, w4) + DOT4(zA5, w5) + DOT4(zA6, w6) + DOT4(zA7, w7);
        sB += DOT4(zB4, w4) + DOT4(zB5, w5) + DOT4(zB6, w6) + DOT4(zB7, w7);
        float4 w8 = wp[8], w9 = wp[9], w10 = wp[10], w11 = wp[11];
        sA += DOT4(zA8, w8) + DOT4(zA9, w9) + DOT4(zA10, w10) + DOT4(zA11, w11);
        sB += DOT4(zB8, w8) + DOT4(zB9, w9) + DOT4(zB10, w10) + DOT4(zB11, w11);
        float4 w12 = wp[12], w13 = wp[13], w14 = wp[14], w15 = wp[15];
        sA += DOT4(zA12, w12) + DOT4(zA13, w13) + DOT4(zA14, w14) + DOT4(zA15, w15);
        sB += DOT4(zB12, w12) + DOT4(zB13, w13) + DOT4(zB14, w14) + DOT4(zB15, w15);
        float wf = w3s[c];
        oA += fmaxf(sA, 0.f) * wf;
        oB += fmaxf(sB, 0.f) * wf;
    }
    float b3 = db3[0];
    if (q < NQ) out[q] = oA + b3;
    if (q + 256 < NQ) out[q + 256] = oB + b3;
}

extern "C" void kernel_launch(void* const* d_in, const int* in_sizes, int n_in,
                              void* d_out, int out_size, void* d_ws, size_t ws_size,
                              hipStream_t stream) {
    const float* x_user = (const float*)d_in[0];
    const float* x_rest = (const float*)d_in[1];
    const float* Wl     = (const float*)d_in[2];
    const float* Wr     = (const float*)d_in[3];
    const float* bl     = (const float*)d_in[4];
    const float* dW1    = (const float*)d_in[5];
    const float* db1    = (const float*)d_in[6];
    const float* dW2    = (const float*)d_in[7];
    const float* db2    = (const float*)d_in[8];
    const float* dW3    = (const float*)d_in[9];
    const float* db3    = (const float*)d_in[10];
    const int* ur_src   = (const int*)d_in[11];
    const int* ur_dst   = (const int*)d_in[12];
    const int* ru_src   = (const int*)d_in[13];
    const int* ru_dst   = (const int*)d_in[14];
    const int* el_row   = (const int*)d_in[15];
    const int* el_col   = (const int*)d_in[16];
    float* out = (float*)d_out;

    char* w = (char*)d_ws;
    size_t off = 0;
    auto alloc = [&](size_t bytes) -> void* {
        void* p = (void*)(w + off);
        off += (bytes + 255) & ~(size_t)255;
        return p;
    };
    float* hu0  = (float*)alloc((size_t)NU * DD * 4);
    float* hu1  = (float*)alloc((size_t)NU * DD * 4);
    float* hr0  = (float*)alloc((size_t)NR * DD * 4);
    float* hr1  = (float*)alloc((size_t)NR * DD * 4);
    float* mean = (float*)alloc((size_t)NU * DD * 4);
    int* csr_u  = (int*)alloc((size_t)NE * 4);
    int* csr_r  = (int*)alloc((size_t)NE * 4);
    int* rs_u   = (int*)alloc((size_t)(NU + 1) * 4);
    int* rs_r   = (int*)alloc((size_t)(NR + 1) * 4);
    int* cnt_u  = (int*)alloc((size_t)NU * 4);
    int* cnt_r  = (int*)alloc((size_t)NR * 4);
    int* bsum_u = (int*)alloc(256 * 4);
    int* bsum_r = (int*)alloc(256 * 4);

    const int nb_u = (NU + SCAN_ITEMS - 1) / SCAN_ITEMS;
    const int nb_r = (NR + SCAN_ITEMS - 1) / SCAN_ITEMS;
    const int egrid = (NE + 255) / 256;

    hipMemsetAsync(cnt_u, 0, (size_t)NU * 4, stream);
    hipMemsetAsync(cnt_r, 0, (size_t)NR * 4, stream);
    count_int_kernel<<<egrid, 256, 0, stream>>>(ru_dst, cnt_u, NE);
    count_int_kernel<<<egrid, 256, 0, stream>>>(ur_dst, cnt_r, NE);
    scan_reduce_kernel<<<nb_u, 256, 0, stream>>>(cnt_u, bsum_u, NU);
    scan_bsum_kernel<<<1, 256, 0, stream>>>(bsum_u, nb_u);
    scan_write_kernel<<<nb_u, 256, 0, stream>>>(cnt_u, bsum_u, rs_u, NU, NE);
    scan_reduce_kernel<<<nb_r, 256, 0, stream>>>(cnt_r, bsum_r, NR);
    scan_bsum_kernel<<<1, 256, 0, stream>>>(bsum_r, nb_r);
    scan_write_kernel<<<nb_r, 256, 0, stream>>>(cnt_r, bsum_r, rs_r, NR, NE);
    hipMemsetAsync(cnt_u, 0, (size_t)NU * 4, stream);
    hipMemsetAsync(cnt_r, 0, (size_t)NR * 4, stream);
    fill_csr_kernel<<<egrid, 256, 0, stream>>>(ru_src, ru_dst, rs_u, cnt_u, csr_u, NE);
    fill_csr_kernel<<<egrid, 256, 0, stream>>>(ur_src, ur_dst, rs_r, cnt_r, csr_r, NE);

    const float* cu = x_user;
    const float* cr = x_rest;
    float* nu_[3] = {hu0, hu1, hu0};
    float* nr_[3] = {hr0, hr1, hr0};

    for (int l = 0; l < 3; l++) {
        const float* Wl_r = Wl + (size_t)(l * 2 + 0) * DD * DD;
        const float* Wr_r = Wr + (size_t)(l * 2 + 0) * DD * DD;
        const float* bl_r = bl + (size_t)(l * 2 + 0) * DD;
        const float* Wl_u = Wl + (size_t)(l * 2 + 1) * DD * DD;
        const float* Wr_u = Wr + (size_t)(l * 2 + 1) * DD * DD;
        const float* bl_u = bl + (size_t)(l * 2 + 1) * DD;
        int relu = (l < 2) ? 1 : 0;

        gather_mean_kernel<<<(NR + 3) / 4, 256, 0, stream>>>(cu, csr_r, rs_r, mean, NR);
        sage_linear_kernel<<<(NR + 255) / 256, 256, 0, stream>>>(mean, cr, Wl_r, Wr_r, bl_r, nr_[l], NR, relu);
        gather_mean_kernel<<<(NU + 3) / 4, 256, 0, stream>>>(cr, csr_u, rs_u, mean, NU);
        sage_linear_kernel<<<(NU + 255) / 256, 256, 0, stream>>>(mean, cu, Wl_u, Wr_u, bl_u, nu_[l], NU, relu);

        cu = nu_[l];
        cr = nr_[l];
    }
    float* P_u = hu1;
    float* P_r = hr1;
    precompute_kernel<<<(NU + 255) / 256, 256, 0, stream>>>(cu, dW1, db1, P_u, NU, 0, 1);
    precompute_kernel<<<(NR + 255) / 256, 256, 0, stream>>>(cr, dW1, db1, P_r, NR, DD, 0);

    decoder_kernel<<<(NQ + 511) / 512, 256, 0, stream>>>(P_u, P_r, el_row, el_col,
                                                         dW2, db2, dW3, db3, out);
}

// Round 12
// 1486.396 us; speedup vs baseline: 1.1208x; 1.0930x over previous
//
#include <hip/hip_runtime.h>

#define NU 200000
#define NR 50000
#define DD 64
#define NE 2000000
#define NQ 500000
#define SCAN_ITEMS 1024
#define NBR 196   // ceil(NR/256)
#define NBU 782   // ceil(NU/256)

// -------------------- fused degree count --------------------
__global__ void count2_kernel(const int* __restrict__ ru_dst, const int* __restrict__ ur_dst,
                              int* __restrict__ cnt_u, int* __restrict__ cnt_r, int n) {
    int i = blockIdx.x * blockDim.x + threadIdx.x;
    if (i < n) {
        atomicAdd(&cnt_u[ru_dst[i]], 1);
        atomicAdd(&cnt_r[ur_dst[i]], 1);
    }
}

// -------------------- fused scan: per-block reduce --------------------
__global__ void scan_reduce_kernel(const int* __restrict__ cnt_u, const int* __restrict__ cnt_r,
                                   int* __restrict__ bsum_u, int* __restrict__ bsum_r,
                                   int nb_u) {
    __shared__ int s[256];
    const int* cnt; int* bsum; int n; int blk;
    if (blockIdx.x < (unsigned)nb_u) { cnt = cnt_u; bsum = bsum_u; n = NU; blk = blockIdx.x; }
    else { cnt = cnt_r; bsum = bsum_r; n = NR; blk = blockIdx.x - nb_u; }
    int base = blk * SCAN_ITEMS;
    int t = 0;
    for (int i = threadIdx.x; i < SCAN_ITEMS; i += 256) {
        int g = base + i;
        t += (g < n) ? cnt[g] : 0;
    }
    s[threadIdx.x] = t;
    __syncthreads();
    for (int off = 128; off > 0; off >>= 1) {
        if (threadIdx.x < off) s[threadIdx.x] += s[threadIdx.x + off];
        __syncthreads();
    }
    if (threadIdx.x == 0) bsum[blk] = s[0];
}

// -------------------- fused scan of block sums (grid=2) --------------------
__global__ void scan_bsum_kernel(int* __restrict__ bsum_u, int* __restrict__ bsum_r,
                                 int nb_u, int nb_r) {
    __shared__ int a[256], b[256];
    int* bsum = (blockIdx.x == 0) ? bsum_u : bsum_r;
    int nb = (blockIdx.x == 0) ? nb_u : nb_r;
    int tid = threadIdx.x;
    a[tid] = (tid < nb) ? bsum[tid] : 0;
    __syncthreads();
    int* cur = a; int* alt = b;
    for (int off = 1; off < 256; off <<= 1) {
        int t = cur[tid];
        if (tid >= off) t += cur[tid - off];
        alt[tid] = t;
        __syncthreads();
        int* tmp = cur; cur = alt; alt = tmp;
    }
    int excl = (tid == 0) ? 0 : cur[tid - 1];
    if (tid < nb) bsum[tid] = excl;
}

// -------------------- fused scan: write exclusive row starts ---------------
__global__ void scan_write_kernel(const int* __restrict__ cnt_u, const int* __restrict__ cnt_r,
                                  const int* __restrict__ bsum_u, const int* __restrict__ bsum_r,
                                  int* __restrict__ rs_u, int* __restrict__ rs_r, int nb_u) {
    __shared__ int sa[256], sb[256];
    const int* cnt; const int* bsum; int* rs; int n; int blk;
    if (blockIdx.x < (unsigned)nb_u) { cnt = cnt_u; bsum = bsum_u; rs = rs_u; n = NU; blk = blockIdx.x; }
    else { cnt = cnt_r; bsum = bsum_r; rs = rs_r; n = NR; blk = blockIdx.x - nb_u; }
    int tid = threadIdx.x;
    int base = blk * SCAN_ITEMS;
    int loc[4];
    int t = 0;
#pragma unroll
    for (int i = 0; i < 4; i++) {
        int g = base + tid * 4 + i;
        int v = (g < n) ? cnt[g] : 0;
        loc[i] = t;
        t += v;
    }
    sa[tid] = t;
    __syncthreads();
    int* cur = sa; int* alt = sb;
    for (int off = 1; off < 256; off <<= 1) {
        int x = cur[tid];
        if (tid >= off) x += cur[tid - off];
        alt[tid] = x;
        __syncthreads();
        int* tmp = cur; cur = alt; alt = tmp;
    }
    int texcl = cur[tid] - t;
    int off0 = bsum[blk] + texcl;
#pragma unroll
    for (int i = 0; i < 4; i++) {
        int g = base + tid * 4 + i;
        if (g < n) rs[g] = off0 + loc[i];
    }
    if (blk == 0 && tid == 0) rs[n] = NE;
}

// -------------------- fused CSR fill --------------------
__global__ void fill2_kernel(const int* __restrict__ ru_src, const int* __restrict__ ru_dst,
                             const int* __restrict__ ur_src, const int* __restrict__ ur_dst,
                             const int* __restrict__ rs_u, const int* __restrict__ rs_r,
                             int* __restrict__ cur_u, int* __restrict__ cur_r,
                             int* __restrict__ csr_u, int* __restrict__ csr_r, int n) {
    int e = blockIdx.x * blockDim.x + threadIdx.x;
    if (e < n) {
        int d = ru_dst[e];
        int pos = atomicAdd(&cur_u[d], 1);
        csr_u[rs_u[d] + pos] = ru_src[e];
        int d2 = ur_dst[e];
        int pos2 = atomicAdd(&cur_r[d2], 1);
        csr_r[rs_r[d2] + pos2] = ur_src[e];
    }
}

// -------------------- fused gather mean: wave per dst row ------------------
__global__ __launch_bounds__(256)
void gather2_kernel(const float* __restrict__ hu, const int* __restrict__ csr_r,
                    const int* __restrict__ rs_r, float* __restrict__ mean_r,
                    const float* __restrict__ hr, const int* __restrict__ csr_u,
                    const int* __restrict__ rs_u, float* __restrict__ mean_u) {
    int lane = threadIdx.x & 63;
    int wave = blockIdx.x * 4 + (threadIdx.x >> 6);
    const float* h; const int* csr; const int* rs; float* mean; int r;
    if (wave < NR) { h = hu; csr = csr_r; rs = rs_r; mean = mean_r; r = wave; }
    else if (wave < NR + NU) { h = hr; csr = csr_u; rs = rs_u; mean = mean_u; r = wave - NR; }
    else return;
    int s = rs[r], e = rs[r + 1];
    float a0 = 0.f, a1 = 0.f, a2 = 0.f, a3 = 0.f;
    for (int j = s; j < e; j += 64) {
        int rem = e - j;
        int nch = rem < 64 ? rem : 64;
        int li = lane < nch ? lane : nch - 1;
        int idx = csr[j + li];
        for (int kk = 0; kk < nch; kk += 4) {
            int i0 = __shfl(idx, kk);
            int i1 = __shfl(idx, kk + 1);
            int i2 = __shfl(idx, kk + 2);
            int i3 = __shfl(idx, kk + 3);
            float v0 = h[i0 * DD + lane];
            float v1 = h[i1 * DD + lane];
            float v2 = h[i2 * DD + lane];
            float v3 = h[i3 * DD + lane];
            a0 += v0;
            a1 += (kk + 1 < nch) ? v1 : 0.f;
            a2 += (kk + 2 < nch) ? v2 : 0.f;
            a3 += (kk + 3 < nch) ? v3 : 0.f;
        }
    }
    float acc = (a0 + a1) + (a2 + a3);
    float inv = 1.0f / fmaxf((float)(e - s), 1.0f);
    mean[r * DD + lane] = acc * inv;
}

// ==== macro toolkit (sage/precompute: 4 rows/thread x 16 cols/wave) ====
#define DOT4(A, B) ((A).x*(B).x + (A).y*(B).y + (A).z*(B).z + (A).w*(B).w)

#define SDECL(j) float sA##j = bsh[cb + (j)], sB##j = sA##j, sC##j = sA##j, sD##j = sA##j;

#define SCOL(j) { \
    const float4* wlp_ = (const float4*)(Wls + ((cb + (j)) << 6) + kc); \
    const float4* wrp_ = (const float4*)(Wrs + ((cb + (j)) << 6) + kc); \
    float4 l0_ = wlp_[0], l1_ = wlp_[1], q0_ = wrp_[0], q1_ = wrp_[1]; \
    sA##j += DOT4(mA0,l0_)+DOT4(mA1,l1_)+DOT4(xA0,q0_)+DOT4(xA1,q1_); \
    sB##j += DOT4(mB0,l0_)+DOT4(mB1,l1_)+DOT4(xB0,q0_)+DOT4(xB1,q1_); \
    sC##j += DOT4(mC0,l0_)+DOT4(mC1,l1_)+DOT4(xC0,q0_)+DOT4(xC1,q1_); \
    sD##j += DOT4(mD0,l0_)+DOT4(mD1,l1_)+DOT4(xD0,q0_)+DOT4(xD1,q1_); }

#define SRELU(j) { sA##j = fmaxf(sA##j,0.f); sB##j = fmaxf(sB##j,0.f); \
                   sC##j = fmaxf(sC##j,0.f); sD##j = fmaxf(sD##j,0.f); }

#define STORE_ROW(SR, rr) if ((rr) < n) { \
    float* o_ = out + (size_t)(rr) * DD + cb; \
    *(float4*)(o_)      = {SR##0,  SR##1,  SR##2,  SR##3}; \
    *(float4*)(o_ + 4)  = {SR##4,  SR##5,  SR##6,  SR##7}; \
    *(float4*)(o_ + 8)  = {SR##8,  SR##9,  SR##10, SR##11}; \
    *(float4*)(o_ + 12) = {SR##12, SR##13, SR##14, SR##15}; }

__device__ __forceinline__
void sage_tile(const float* __restrict__ mean, const float* __restrict__ h,
               const float* Wls, const float* Wrs, const float* bsh,
               float* __restrict__ out, int n, int do_relu, int r0, int cb) {
    int rA = min(r0, n - 1), rB = min(r0 + 64, n - 1);
    int rC = min(r0 + 128, n - 1), rD = min(r0 + 192, n - 1);
    const float *mA = mean + (size_t)rA * DD, *xA = h + (size_t)rA * DD;
    const float *mB = mean + (size_t)rB * DD, *xB = h + (size_t)rB * DD;
    const float *mC = mean + (size_t)rC * DD, *xC = h + (size_t)rC * DD;
    const float *mD = mean + (size_t)rD * DD, *xD = h + (size_t)rD * DD;
    SDECL(0)  SDECL(1)  SDECL(2)  SDECL(3)  SDECL(4)  SDECL(5)  SDECL(6)  SDECL(7)
    SDECL(8)  SDECL(9)  SDECL(10) SDECL(11) SDECL(12) SDECL(13) SDECL(14) SDECL(15)
#pragma unroll 1
    for (int kc = 0; kc < DD; kc += 8) {
        float4 mA0 = *(const float4*)(mA + kc), mA1 = *(const float4*)(mA + kc + 4);
        float4 xA0 = *(const float4*)(xA + kc), xA1 = *(const float4*)(xA + kc + 4);
        float4 mB0 = *(const float4*)(mB + kc), mB1 = *(const float4*)(mB + kc + 4);
        float4 xB0 = *(const float4*)(xB + kc), xB1 = *(const float4*)(xB + kc + 4);
        float4 mC0 = *(const float4*)(mC + kc), mC1 = *(const float4*)(mC + kc + 4);
        float4 xC0 = *(const float4*)(xC + kc), xC1 = *(const float4*)(xC + kc + 4);
        float4 mD0 = *(const float4*)(mD + kc), mD1 = *(const float4*)(mD + kc + 4);
        float4 xD0 = *(const float4*)(xD + kc), xD1 = *(const float4*)(xD + kc + 4);
        SCOL(0)  SCOL(1)  SCOL(2)  SCOL(3)  SCOL(4)  SCOL(5)  SCOL(6)  SCOL(7)
        SCOL(8)  SCOL(9)  SCOL(10) SCOL(11) SCOL(12) SCOL(13) SCOL(14) SCOL(15)
    }
    if (do_relu) {
        SRELU(0)  SRELU(1)  SRELU(2)  SRELU(3)  SRELU(4)  SRELU(5)  SRELU(6)  SRELU(7)
        SRELU(8)  SRELU(9)  SRELU(10) SRELU(11) SRELU(12) SRELU(13) SRELU(14) SRELU(15)
    }
    STORE_ROW(sA, r0)
    STORE_ROW(sB, r0 + 64)
    STORE_ROW(sC, r0 + 128)
    STORE_ROW(sD, r0 + 192)
}

// -------------------- fused SAGE linear (both sides, one launch) -----------
__global__ __launch_bounds__(256, 2)
void sage_fused_kernel(const float* __restrict__ mean_r, const float* __restrict__ hr,
                       const float* __restrict__ mean_u, const float* __restrict__ hu,
                       const float* __restrict__ Wl2, const float* __restrict__ Wr2,
                       const float* __restrict__ bl2,
                       float* __restrict__ out_r, float* __restrict__ out_u, int do_relu) {
    __shared__ float Wls[DD * DD];
    __shared__ float Wrs[DD * DD];
    __shared__ float bsh[DD];
    int side = (blockIdx.x < NBR) ? 0 : 1;
    const float* Wl = Wl2 + side * DD * DD;
    const float* Wr = Wr2 + side * DD * DD;
    const float* bl = bl2 + side * DD;
    for (int i = threadIdx.x; i < DD * DD; i += 256) {
        Wls[i] = Wl[i];
        Wrs[i] = Wr[i];
    }
    if (threadIdx.x < DD) bsh[threadIdx.x] = bl[threadIdx.x];
    __syncthreads();
    int lane = threadIdx.x & 63;
    int cb = (threadIdx.x >> 6) * 16;
    if (side == 0) {
        int r0 = blockIdx.x * 256 + lane;
        sage_tile(mean_r, hr, Wls, Wrs, bsh, out_r, NR, do_relu, r0, cb);
    } else {
        int r0 = (blockIdx.x - NBR) * 256 + lane;
        sage_tile(mean_u, hu, Wls, Wrs, bsh, out_u, NU, do_relu, r0, cb);
    }
}

// -------------------- fused decoder layer-1 precompute ---------------------
#define PCOL(j) { \
    const float4* wp_ = (const float4*)(Ws + ((cb + (j)) << 6) + kc); \
    float4 w0_ = wp_[0], w1_ = wp_[1]; \
    sA##j += DOT4(xA0,w0_)+DOT4(xA1,w1_); \
    sB##j += DOT4(xB0,w0_)+DOT4(xB1,w1_); \
    sC##j += DOT4(xC0,w0_)+DOT4(xC1,w1_); \
    sD##j += DOT4(xD0,w0_)+DOT4(xD1,w1_); }

__device__ __forceinline__
void pre_tile(const float* __restrict__ h, const float* Ws, const float* bsh,
              float* __restrict__ out, int n, int r0, int cb) {
    int rA = min(r0, n - 1), rB = min(r0 + 64, n - 1);
    int rC = min(r0 + 128, n - 1), rD = min(r0 + 192, n - 1);
    const float *xA = h + (size_t)rA * DD, *xB = h + (size_t)rB * DD;
    const float *xC = h + (size_t)rC * DD, *xD = h + (size_t)rD * DD;
    SDECL(0)  SDECL(1)  SDECL(2)  SDECL(3)  SDECL(4)  SDECL(5)  SDECL(6)  SDECL(7)
    SDECL(8)  SDECL(9)  SDECL(10) SDECL(11) SDECL(12) SDECL(13) SDECL(14) SDECL(15)
#pragma unroll 1
    for (int kc = 0; kc < DD; kc += 8) {
        float4 xA0 = *(const float4*)(xA + kc), xA1 = *(const float4*)(xA + kc + 4);
        float4 xB0 = *(const float4*)(xB + kc), xB1 = *(const float4*)(xB + kc + 4);
        float4 xC0 = *(const float4*)(xC + kc), xC1 = *(const float4*)(xC + kc + 4);
        float4 xD0 = *(const float4*)(xD + kc), xD1 = *(const float4*)(xD + kc + 4);
        PCOL(0)  PCOL(1)  PCOL(2)  PCOL(3)  PCOL(4)  PCOL(5)  PCOL(6)  PCOL(7)
        PCOL(8)  PCOL(9)  PCOL(10) PCOL(11) PCOL(12) PCOL(13) PCOL(14) PCOL(15)
    }
    STORE_ROW(sA, r0)
    STORE_ROW(sB, r0 + 64)
    STORE_ROW(sC, r0 + 128)
    STORE_ROW(sD, r0 + 192)
}

__global__ __launch_bounds__(256, 2)
void pre_fused_kernel(const float* __restrict__ hu, const float* __restrict__ hr,
                      const float* __restrict__ dW1, const float* __restrict__ db1,
                      float* __restrict__ P_u, float* __restrict__ P_r) {
    __shared__ float Ws[DD * DD];
    __shared__ float bsh[DD];
    int side = (blockIdx.x < NBU) ? 0 : 1;   // 0 = user (koff 0, bias), 1 = rest
    int koff = side ? DD : 0;
    for (int i = threadIdx.x; i < DD * DD; i += 256) {
        int c = i >> 6, k = i & 63;
        Ws[c * DD + k] = dW1[c * 2 * DD + koff + k];
    }
    if (threadIdx.x < DD) bsh[threadIdx.x] = side ? 0.f : db1[threadIdx.x];
    __syncthreads();
    int lane = threadIdx.x & 63;
    int cb = (threadIdx.x >> 6) * 16;
    if (side == 0) {
        int r0 = blockIdx.x * 256 + lane;
        pre_tile(hu, Ws, bsh, P_u, NU, r0, cb);
    } else {
        int r0 = (blockIdx.x - NBU) * 256 + lane;
        pre_tile(hr, Ws, bsh, P_r, NR, r0, cb);
    }
}

// -------------------- fused decoder: thread per query (R8 form) ------------
#define ZCOMB(Zi, i) float4 Zi; { float4 u_ = pu[i]; float4 v_ = pr[i]; \
    Zi.x = fmaxf(u_.x + v_.x, 0.f); Zi.y = fmaxf(u_.y + v_.y, 0.f); \
    Zi.z = fmaxf(u_.z + v_.z, 0.f); Zi.w = fmaxf(u_.w + v_.w, 0.f); }

__global__ __launch_bounds__(256, 2)
void decoder_kernel(const float* __restrict__ Pu, const float* __restrict__ Pr,
                    const int* __restrict__ el_row, const int* __restrict__ el_col,
                    const float* __restrict__ dW2, const float* __restrict__ db2,
                    const float* __restrict__ dW3, const float* __restrict__ db3,
                    float* __restrict__ out) {
    __shared__ float W2s[DD * DD];
    __shared__ float b2s[DD], w3s[DD];
    for (int i = threadIdx.x; i < DD * DD; i += 256) W2s[i] = dW2[i];
    if (threadIdx.x < DD) {
        b2s[threadIdx.x] = db2[threadIdx.x];
        w3s[threadIdx.x] = dW3[threadIdx.x];
    }
    __syncthreads();
    int q = blockIdx.x * 256 + threadIdx.x;
    if (q >= NQ) return;
    int row = el_row[q], col = el_col[q];
    const float4* pu = (const float4*)(Pu + (size_t)row * DD);
    const float4* pr = (const float4*)(Pr + (size_t)col * DD);
    ZCOMB(z0, 0)  ZCOMB(z1, 1)  ZCOMB(z2, 2)  ZCOMB(z3, 3)
    ZCOMB(z4, 4)  ZCOMB(z5, 5)  ZCOMB(z6, 6)  ZCOMB(z7, 7)
    ZCOMB(z8, 8)  ZCOMB(z9, 9)  ZCOMB(z10, 10) ZCOMB(z11, 11)
    ZCOMB(z12, 12) ZCOMB(z13, 13) ZCOMB(z14, 14) ZCOMB(z15, 15)
    float o = db3[0];
#pragma unroll 2
    for (int c = 0; c < DD; c++) {
        const float4* wp = (const float4*)(W2s + c * DD);  // broadcast, conflict-free
        float s = b2s[c]
            + DOT4(z0, wp[0])  + DOT4(z1, wp[1])  + DOT4(z2, wp[2])  + DOT4(z3, wp[3])
            + DOT4(z4, wp[4])  + DOT4(z5, wp[5])  + DOT4(z6, wp[6])  + DOT4(z7, wp[7])
            + DOT4(z8, wp[8])  + DOT4(z9, wp[9])  + DOT4(z10, wp[10]) + DOT4(z11, wp[11])
            + DOT4(z12, wp[12]) + DOT4(z13, wp[13]) + DOT4(z14, wp[14]) + DOT4(z15, wp[15]);
        o += fmaxf(s, 0.f) * w3s[c];
    }
    out[q] = o;
}

extern "C" void kernel_launch(void* const* d_in, const int* in_sizes, int n_in,
                              void* d_out, int out_size, void* d_ws, size_t ws_size,
                              hipStream_t stream) {
    const float* x_user = (const float*)d_in[0];
    const float* x_rest = (const float*)d_in[1];
    const float* Wl     = (const float*)d_in[2];
    const float* Wr     = (const float*)d_in[3];
    const float* bl     = (const float*)d_in[4];
    const float* dW1    = (const float*)d_in[5];
    const float* db1    = (const float*)d_in[6];
    const float* dW2    = (const float*)d_in[7];
    const float* db2    = (const float*)d_in[8];
    const float* dW3    = (const float*)d_in[9];
    const float* db3    = (const float*)d_in[10];
    const int* ur_src   = (const int*)d_in[11];
    const int* ur_dst   = (const int*)d_in[12];
    const int* ru_src   = (const int*)d_in[13];
    const int* ru_dst   = (const int*)d_in[14];
    const int* el_row   = (const int*)d_in[15];
    const int* el_col   = (const int*)d_in[16];
    float* out = (float*)d_out;

    char* w = (char*)d_ws;
    size_t off = 0;
    auto alloc = [&](size_t bytes) -> void* {
        void* p = (void*)(w + off);
        off += (bytes + 255) & ~(size_t)255;
        return p;
    };
    float* hu0    = (float*)alloc((size_t)NU * DD * 4);
    float* hu1    = (float*)alloc((size_t)NU * DD * 4);
    float* hr0    = (float*)alloc((size_t)NR * DD * 4);
    float* hr1    = (float*)alloc((size_t)NR * DD * 4);
    float* mean_u = (float*)alloc((size_t)NU * DD * 4);
    float* mean_r = (float*)alloc((size_t)NR * DD * 4);
    int* csr_u  = (int*)alloc((size_t)NE * 4);
    int* csr_r  = (int*)alloc((size_t)NE * 4);
    int* rs_u   = (int*)alloc((size_t)(NU + 1) * 4);
    int* rs_r   = (int*)alloc((size_t)(NR + 1) * 4);
    int* cnt_u  = (int*)alloc((size_t)NU * 4);   // NU*4 = 800000, 256-aligned ->
    int* cnt_r  = (int*)alloc((size_t)NR * 4);   // cnt_r contiguous after cnt_u
    int* bsum_u = (int*)alloc(256 * 4);
    int* bsum_r = (int*)alloc(256 * 4);

    const int nb_u = (NU + SCAN_ITEMS - 1) / SCAN_ITEMS;  // 196
    const int nb_r = (NR + SCAN_ITEMS - 1) / SCAN_ITEMS;  // 49
    const int egrid = (NE + 255) / 256;

    // ---- CSR build (fused kernels; cnt_u/cnt_r zeroed with one memset) ----
    hipMemsetAsync(cnt_u, 0, (size_t)(NU + NR) * 4, stream);
    count2_kernel<<<egrid, 256, 0, stream>>>(ru_dst, ur_dst, cnt_u, cnt_r, NE);
    scan_reduce_kernel<<<nb_u + nb_r, 256, 0, stream>>>(cnt_u, cnt_r, bsum_u, bsum_r, nb_u);
    scan_bsum_kernel<<<2, 256, 0, stream>>>(bsum_u, bsum_r, nb_u, nb_r);
    scan_write_kernel<<<nb_u + nb_r, 256, 0, stream>>>(cnt_u, cnt_r, bsum_u, bsum_r, rs_u, rs_r, nb_u);
    hipMemsetAsync(cnt_u, 0, (size_t)(NU + NR) * 4, stream);
    fill2_kernel<<<egrid, 256, 0, stream>>>(ru_src, ru_dst, ur_src, ur_dst,
                                            rs_u, rs_r, cnt_u, cnt_r, csr_u, csr_r, NE);

    // ---- 3 SAGE layers: 2 fused launches per layer ----
    const float* cu = x_user;
    const float* cr = x_rest;
    float* nu_[3] = {hu0, hu1, hu0};
    float* nr_[3] = {hr0, hr1, hr0};
    const int ggrid = (NR + NU + 3) / 4;   // 62500

    for (int l = 0; l < 3; l++) {
        const float* Wl2 = Wl + (size_t)l * 2 * DD * DD;
        const float* Wr2 = Wr + (size_t)l * 2 * DD * DD;
        const float* bl2 = bl + (size_t)l * 2 * DD;
        int relu = (l < 2) ? 1 : 0;
        gather2_kernel<<<ggrid, 256, 0, stream>>>(cu, csr_r, rs_r, mean_r,
                                                  cr, csr_u, rs_u, mean_u);
        sage_fused_kernel<<<NBR + NBU, 256, 0, stream>>>(mean_r, cr, mean_u, cu,
                                                         Wl2, Wr2, bl2,
                                                         nr_[l], nu_[l], relu);
        cu = nu_[l];
        cr = nr_[l];
    }
    // ---- decoder ----
    float* P_u = hu1;
    float* P_r = hr1;
    pre_fused_kernel<<<NBU + NBR, 256, 0, stream>>>(cu, cr, dW1, db1, P_u, P_r);
    decoder_kernel<<<(NQ + 255) / 256, 256, 0, stream>>>(P_u, P_r, el_row, el_col,
                                                         dW2, db2, dW3, db3, out);
}